// Round 2
// baseline (791.995 us; speedup 1.0000x reference)
//
#include <hip/hip_runtime.h>

// ---------- helpers: order-preserving float<->uint encoding for atomicMax ----
__device__ __forceinline__ unsigned fenc(float f) {
    unsigned u = __float_as_uint(f);
    return (u & 0x80000000u) ? ~u : (u | 0x80000000u);
}
__device__ __forceinline__ float fdec(unsigned e) {
    unsigned u = (e & 0x80000000u) ? (e ^ 0x80000000u) : ~e;
    return __uint_as_float(u);
}

// ---------- init: out = bias (broadcast), m = 0 (== below -inf), denom = 0 --
__global__ __launch_bounds__(256) void k_init(
    float* __restrict__ out_user, float* __restrict__ out_item,
    const float* __restrict__ bias_i2u, const float* __restrict__ bias_u2i,
    unsigned* __restrict__ m_u2i, float* __restrict__ dn_u2i,
    unsigned* __restrict__ m_i2u, float* __restrict__ dn_i2u,
    int n_user, int n_item)
{
    int i = blockIdx.x * 256 + threadIdx.x;
    int nu64 = n_user * 64;
    int ni64 = n_item * 64;
    if (i < nu64) {
        out_user[i] = bias_i2u[i & 63];
    } else if (i < nu64 + ni64) {
        int j = i - nu64;
        out_item[j] = bias_u2i[j & 63];
    }
    if (i < n_item * 2) { m_u2i[i] = 0u; dn_u2i[i] = 0.0f; }
    if (i < n_user * 2) { m_i2u[i] = 0u; dn_i2u[i] = 0.0f; }
}

// ---------- GEMM: Y[M,128] = X[M,128] @ W[128,128] + B[128]  (fp32 vector) ---
// 64-row x 128-col tile per block, 256 threads, K chunked by 32.
__global__ __launch_bounds__(256) void gemm128(
    const float* __restrict__ X, const float* __restrict__ W,
    const float* __restrict__ Bv, float* __restrict__ Y, int M)
{
    __shared__ float xs[64][36];    // +4 pad: bank-spread, keeps 16B alignment
    __shared__ float ws[32][128];

    const int tid = threadIdx.x;
    const int m0  = blockIdx.x * 64;
    const int r0  = (tid >> 4) * 4;   // 0..60
    const int c0  = (tid & 15) * 4;   // 0..60 ; cols {c0..c0+3, c0+64..c0+67}

    float acc[4][8];
#pragma unroll
    for (int i = 0; i < 4; ++i)
#pragma unroll
        for (int j = 0; j < 8; ++j) acc[i][j] = 0.0f;

    for (int kc = 0; kc < 128; kc += 32) {
        // load X tile: 64 rows x 32 k  (512 float4, 2 per thread)
#pragma unroll
        for (int i = 0; i < 2; ++i) {
            int f = tid + i * 256;
            int row = f >> 3;
            int kq  = (f & 7) * 4;
            float4 v = make_float4(0.f, 0.f, 0.f, 0.f);
            if (m0 + row < M)
                v = *(const float4*)&X[(size_t)(m0 + row) * 128 + kc + kq];
            *(float4*)&xs[row][kq] = v;
        }
        // load W tile: 32 k x 128 n  (1024 float4, 4 per thread)
#pragma unroll
        for (int i = 0; i < 4; ++i) {
            int f = tid + i * 256;
            int k  = f >> 5;
            int nq = (f & 31) * 4;
            *(float4*)&ws[k][nq] = *(const float4*)&W[(size_t)(kc + k) * 128 + nq];
        }
        __syncthreads();

#pragma unroll
        for (int k = 0; k < 32; k += 4) {
            float4 a0 = *(const float4*)&xs[r0 + 0][k];
            float4 a1 = *(const float4*)&xs[r0 + 1][k];
            float4 a2 = *(const float4*)&xs[r0 + 2][k];
            float4 a3 = *(const float4*)&xs[r0 + 3][k];
#pragma unroll
            for (int kk = 0; kk < 4; ++kk) {
                float4 b0 = *(const float4*)&ws[k + kk][c0];
                float4 b1 = *(const float4*)&ws[k + kk][c0 + 64];
                float bx0 = b0.x, bx1 = b0.y, bx2 = b0.z, bx3 = b0.w;
                float bx4 = b1.x, bx5 = b1.y, bx6 = b1.z, bx7 = b1.w;
                float av0 = ((const float*)&a0)[kk];
                float av1 = ((const float*)&a1)[kk];
                float av2 = ((const float*)&a2)[kk];
                float av3 = ((const float*)&a3)[kk];
                acc[0][0] += av0 * bx0; acc[0][1] += av0 * bx1;
                acc[0][2] += av0 * bx2; acc[0][3] += av0 * bx3;
                acc[0][4] += av0 * bx4; acc[0][5] += av0 * bx5;
                acc[0][6] += av0 * bx6; acc[0][7] += av0 * bx7;
                acc[1][0] += av1 * bx0; acc[1][1] += av1 * bx1;
                acc[1][2] += av1 * bx2; acc[1][3] += av1 * bx3;
                acc[1][4] += av1 * bx4; acc[1][5] += av1 * bx5;
                acc[1][6] += av1 * bx6; acc[1][7] += av1 * bx7;
                acc[2][0] += av2 * bx0; acc[2][1] += av2 * bx1;
                acc[2][2] += av2 * bx2; acc[2][3] += av2 * bx3;
                acc[2][4] += av2 * bx4; acc[2][5] += av2 * bx5;
                acc[2][6] += av2 * bx6; acc[2][7] += av2 * bx7;
                acc[3][0] += av3 * bx0; acc[3][1] += av3 * bx1;
                acc[3][2] += av3 * bx2; acc[3][3] += av3 * bx3;
                acc[3][4] += av3 * bx4; acc[3][5] += av3 * bx5;
                acc[3][6] += av3 * bx6; acc[3][7] += av3 * bx7;
            }
        }
        __syncthreads();
    }

    float4 bb0 = *(const float4*)&Bv[c0];
    float4 bb1 = *(const float4*)&Bv[c0 + 64];
#pragma unroll
    for (int i = 0; i < 4; ++i) {
        int row = m0 + r0 + i;
        if (row < M) {
            float4 o0 = make_float4(acc[i][0] + bb0.x, acc[i][1] + bb0.y,
                                    acc[i][2] + bb0.z, acc[i][3] + bb0.w);
            float4 o1 = make_float4(acc[i][4] + bb1.x, acc[i][5] + bb1.y,
                                    acc[i][6] + bb1.z, acc[i][7] + bb1.w);
            *(float4*)&Y[(size_t)row * 128 + c0]      = o0;
            *(float4*)&Y[(size_t)row * 128 + c0 + 64] = o1;
        }
    }
}

// ---------- edge logits + fused segment max: one wave per edge --------------
// Lane layout: 32 lanes per head (h = lane>>5, j = lane&31); each lane covers
// channels j and j+32 of its head -> 5-step shfl reduce within the 32-half.
__global__ __launch_bounds__(256) void k_logits(
    const float* __restrict__ xl, const float* __restrict__ xr,
    const int* __restrict__ src, const int* __restrict__ dst,
    const float* __restrict__ att, float* __restrict__ logits,
    unsigned* __restrict__ m, int E)
{
    int gt = blockIdx.x * 256 + threadIdx.x;
    int e  = gt >> 6;
    if (e >= E) return;
    int lane = threadIdx.x & 63;
    int h = lane >> 5;        // head
    int j = lane & 31;        // channel within head (also +32)
    int c0 = h * 64 + j;
    int c1 = c0 + 32;
    int s = src[e], d = dst[e];
    const float* xjp = xl + (size_t)s * 128;
    const float* xip = xr + (size_t)d * 128;
    float v0 = xip[c0] + xjp[c0];
    float v1 = xip[c1] + xjp[c1];
    v0 = v0 >= 0.f ? v0 : 0.2f * v0;
    v1 = v1 >= 0.f ? v1 : 0.2f * v1;
    float p = v0 * att[c0] + v1 * att[c1];
#pragma unroll
    for (int off = 16; off > 0; off >>= 1)
        p += __shfl_xor(p, off, 64);
    if (j == 0) {
        logits[(size_t)e * 2 + h] = p;
        atomicMax(&m[(size_t)d * 2 + h], fenc(p));
    }
}

// ---------- segment denom ---------------------------------------------------
__global__ __launch_bounds__(256) void k_denom(
    const float* __restrict__ logits, const int* __restrict__ dst,
    const unsigned* __restrict__ m, float* __restrict__ denom, int E)
{
    int i = blockIdx.x * 256 + threadIdx.x;
    if (i >= E * 2) return;
    int e = i >> 1, h = i & 1;
    int d = dst[e];
    float a = __expf(logits[i] - fdec(m[(size_t)d * 2 + h]));
    atomicAdd(&denom[(size_t)d * 2 + h], a);
}

// ---------- scatter: out[dst] += mean_h(alpha_h * xj_h); one wave per edge --
__global__ __launch_bounds__(256) void k_scatter(
    const float* __restrict__ xl, const float* __restrict__ logits,
    const int* __restrict__ src, const int* __restrict__ dst,
    const unsigned* __restrict__ m, const float* __restrict__ denom,
    float* __restrict__ out, int E)
{
    int gt = blockIdx.x * 256 + threadIdx.x;
    int e  = gt >> 6;
    if (e >= E) return;
    int lane = threadIdx.x & 63;
    int s = src[e], d = dst[e];
    float l0 = logits[(size_t)e * 2];
    float l1 = logits[(size_t)e * 2 + 1];
    float a0 = __expf(l0 - fdec(m[(size_t)d * 2]))     / (denom[(size_t)d * 2]     + 1e-16f) * 0.5f;
    float a1 = __expf(l1 - fdec(m[(size_t)d * 2 + 1])) / (denom[(size_t)d * 2 + 1] + 1e-16f) * 0.5f;
    const float* xjp = xl + (size_t)s * 128;
    float c = a0 * xjp[lane] + a1 * xjp[lane + 64];
    atomicAdd(&out[(size_t)d * 64 + lane], c);
}

extern "C" void kernel_launch(void* const* d_in, const int* in_sizes, int n_in,
                              void* d_out, int out_size, void* d_ws, size_t ws_size,
                              hipStream_t stream)
{
    const float* x_user   = (const float*)d_in[0];
    const float* x_item   = (const float*)d_in[1];
    const int*   src_u2i  = (const int*)d_in[2];
    const int*   dst_u2i  = (const int*)d_in[3];
    const int*   src_i2u  = (const int*)d_in[4];
    const int*   dst_i2u  = (const int*)d_in[5];
    const float* Wl_u2i   = (const float*)d_in[6];
    const float* bl_u2i   = (const float*)d_in[7];
    const float* Wr_u2i   = (const float*)d_in[8];
    const float* br_u2i   = (const float*)d_in[9];
    const float* att_u2i  = (const float*)d_in[10];
    const float* bias_u2i = (const float*)d_in[11];
    const float* Wl_i2u   = (const float*)d_in[12];
    const float* bl_i2u   = (const float*)d_in[13];
    const float* Wr_i2u   = (const float*)d_in[14];
    const float* br_i2u   = (const float*)d_in[15];
    const float* att_i2u  = (const float*)d_in[16];
    const float* bias_i2u = (const float*)d_in[17];

    const int n_user = in_sizes[0] / 128;
    const int n_item = in_sizes[1] / 128;
    const int E      = in_sizes[2];

    float* out_user = (float*)d_out;                       // [n_user,64] (from i2u)
    float* out_item = out_user + (size_t)n_user * 64;      // [n_item,64] (from u2i)

    char* w = (char*)d_ws;
    float* xl_u2i = (float*)w; w += (size_t)n_user * 128 * 4;  // x_user @ Wl_u2i
    float* xr_u2i = (float*)w; w += (size_t)n_item * 128 * 4;  // x_item @ Wr_u2i
    float* xl_i2u = (float*)w; w += (size_t)n_item * 128 * 4;  // x_item @ Wl_i2u
    float* xr_i2u = (float*)w; w += (size_t)n_user * 128 * 4;  // x_user @ Wr_i2u
    float*    lg_u2i = (float*)w;    w += (size_t)E * 2 * 4;
    float*    lg_i2u = (float*)w;    w += (size_t)E * 2 * 4;
    unsigned* m_u2i  = (unsigned*)w; w += (size_t)n_item * 2 * 4;
    float*    dn_u2i = (float*)w;    w += (size_t)n_item * 2 * 4;
    unsigned* m_i2u  = (unsigned*)w; w += (size_t)n_user * 2 * 4;
    float*    dn_i2u = (float*)w;    w += (size_t)n_user * 2 * 4;

    // init out=bias, m=-inf(enc 0), denom=0
    int totalInit = n_user * 64 + n_item * 64;
    k_init<<<(totalInit + 255) / 256, 256, 0, stream>>>(
        out_user, out_item, bias_i2u, bias_u2i,
        m_u2i, dn_u2i, m_i2u, dn_i2u, n_user, n_item);

    // node linear transforms
    gemm128<<<(n_user + 63) / 64, 256, 0, stream>>>(x_user, Wl_u2i, bl_u2i, xl_u2i, n_user);
    gemm128<<<(n_item + 63) / 64, 256, 0, stream>>>(x_item, Wr_u2i, br_u2i, xr_u2i, n_item);
    gemm128<<<(n_item + 63) / 64, 256, 0, stream>>>(x_item, Wl_i2u, bl_i2u, xl_i2u, n_item);
    gemm128<<<(n_user + 63) / 64, 256, 0, stream>>>(x_user, Wr_i2u, br_i2u, xr_i2u, n_user);

    // edge logits + fused segment max (one wave per edge)
    int ewBlocks = (E + 3) / 4;
    k_logits<<<ewBlocks, 256, 0, stream>>>(xl_u2i, xr_u2i, src_u2i, dst_u2i, att_u2i, lg_u2i, m_u2i, E);
    k_logits<<<ewBlocks, 256, 0, stream>>>(xl_i2u, xr_i2u, src_i2u, dst_i2u, att_i2u, lg_i2u, m_i2u, E);

    // segment denom
    int e2Blocks = (E * 2 + 255) / 256;
    k_denom<<<e2Blocks, 256, 0, stream>>>(lg_u2i, dst_u2i, m_u2i, dn_u2i, E);
    k_denom<<<e2Blocks, 256, 0, stream>>>(lg_i2u, dst_i2u, m_i2u, dn_i2u, E);

    // weighted scatter into outputs
    k_scatter<<<ewBlocks, 256, 0, stream>>>(xl_u2i, lg_u2i, src_u2i, dst_u2i, m_u2i, dn_u2i, out_item, E);
    k_scatter<<<ewBlocks, 256, 0, stream>>>(xl_i2u, lg_i2u, src_i2u, dst_i2u, m_i2u, dn_i2u, out_user, E);
}

// Round 3
// 507.551 us; speedup vs baseline: 1.5604x; 1.5604x over previous
//
#include <hip/hip_runtime.h>

#define SCAN_B 1024

// ---------------- CSR build ----------------
__global__ __launch_bounds__(256) void k_zero(int* __restrict__ cnt, int n) {
    int i = blockIdx.x * 256 + threadIdx.x;
    if (i < n) cnt[i] = 0;
}

// histogram over both edge types; cnt layout: [0,n_a) = dir A, [n_a, n_a+n_b) = dir B
__global__ __launch_bounds__(256) void k_hist(
    const int* __restrict__ dst_a, const int* __restrict__ dst_b,
    int* __restrict__ cnt, int n_a, int E)
{
    int i = blockIdx.x * 256 + threadIdx.x;
    if (i >= 2 * E) return;
    int idx = (i < E) ? dst_a[i] : (n_a + dst_b[i - E]);
    atomicAdd(&cnt[idx], 1);
}

__global__ __launch_bounds__(SCAN_B) void k_scan1(
    const int* __restrict__ cnt, int n, int* __restrict__ rowptr, int* __restrict__ bsum)
{
    __shared__ int tmp[SCAN_B];
    int i = blockIdx.x * SCAN_B + threadIdx.x;
    int v = (i < n) ? cnt[i] : 0;
    tmp[threadIdx.x] = v;
    __syncthreads();
    for (int off = 1; off < SCAN_B; off <<= 1) {
        int t = (threadIdx.x >= (unsigned)off) ? tmp[threadIdx.x - off] : 0;
        __syncthreads();
        tmp[threadIdx.x] += t;
        __syncthreads();
    }
    if (i < n) rowptr[i] = tmp[threadIdx.x] - v;   // exclusive
    if (threadIdx.x == SCAN_B - 1) bsum[blockIdx.x] = tmp[threadIdx.x];
}

__global__ __launch_bounds__(SCAN_B) void k_scan2(int* __restrict__ bsum, int nb) {
    __shared__ int tmp[SCAN_B];
    int i = threadIdx.x;
    int v = (i < nb) ? bsum[i] : 0;
    tmp[i] = v;
    __syncthreads();
    for (int off = 1; off < SCAN_B; off <<= 1) {
        int t = (i >= off) ? tmp[i - off] : 0;
        __syncthreads();
        tmp[i] += t;
        __syncthreads();
    }
    if (i < nb) bsum[i] = tmp[i] - v;              // exclusive
}

__global__ __launch_bounds__(256) void k_scan3(
    int* __restrict__ rowptr, int* __restrict__ cursor,
    const int* __restrict__ bsum, int n, int total)
{
    int i = blockIdx.x * 256 + threadIdx.x;
    if (i < n) {
        int r = rowptr[i] + bsum[i / SCAN_B];
        rowptr[i] = r;
        cursor[i] = r;
    }
    if (i == 0) rowptr[n] = total;
}

__global__ __launch_bounds__(256) void k_fill(
    const int* __restrict__ src_a, const int* __restrict__ dst_a,
    const int* __restrict__ src_b, const int* __restrict__ dst_b,
    int* __restrict__ cursor, int* __restrict__ sorted_src, int n_a, int E)
{
    int i = blockIdx.x * 256 + threadIdx.x;
    if (i >= 2 * E) return;
    int idx, s;
    if (i < E) { idx = dst_a[i];            s = src_a[i]; }
    else       { idx = n_a + dst_b[i - E];  s = src_b[i - E]; }
    int pos = atomicAdd(&cursor[idx], 1);
    sorted_src[pos] = s;
}

// ---------- GEMM: Y[M,128] = X[M,128] @ W[128,128] + B[128]  (fp32 vector) ---
__global__ __launch_bounds__(256) void gemm128(
    const float* __restrict__ X, const float* __restrict__ W,
    const float* __restrict__ Bv, float* __restrict__ Y, int M)
{
    __shared__ float xs[64][36];
    __shared__ float ws[32][128];

    const int tid = threadIdx.x;
    const int m0  = blockIdx.x * 64;
    const int r0  = (tid >> 4) * 4;
    const int c0  = (tid & 15) * 4;

    float acc[4][8];
#pragma unroll
    for (int i = 0; i < 4; ++i)
#pragma unroll
        for (int j = 0; j < 8; ++j) acc[i][j] = 0.0f;

    for (int kc = 0; kc < 128; kc += 32) {
#pragma unroll
        for (int i = 0; i < 2; ++i) {
            int f = tid + i * 256;
            int row = f >> 3;
            int kq  = (f & 7) * 4;
            float4 v = make_float4(0.f, 0.f, 0.f, 0.f);
            if (m0 + row < M)
                v = *(const float4*)&X[(size_t)(m0 + row) * 128 + kc + kq];
            *(float4*)&xs[row][kq] = v;
        }
#pragma unroll
        for (int i = 0; i < 4; ++i) {
            int f = tid + i * 256;
            int k  = f >> 5;
            int nq = (f & 31) * 4;
            *(float4*)&ws[k][nq] = *(const float4*)&W[(size_t)(kc + k) * 128 + nq];
        }
        __syncthreads();

#pragma unroll
        for (int k = 0; k < 32; k += 4) {
            float4 a0 = *(const float4*)&xs[r0 + 0][k];
            float4 a1 = *(const float4*)&xs[r0 + 1][k];
            float4 a2 = *(const float4*)&xs[r0 + 2][k];
            float4 a3 = *(const float4*)&xs[r0 + 3][k];
#pragma unroll
            for (int kk = 0; kk < 4; ++kk) {
                float4 b0 = *(const float4*)&ws[k + kk][c0];
                float4 b1 = *(const float4*)&ws[k + kk][c0 + 64];
                float bx0 = b0.x, bx1 = b0.y, bx2 = b0.z, bx3 = b0.w;
                float bx4 = b1.x, bx5 = b1.y, bx6 = b1.z, bx7 = b1.w;
                float av0 = ((const float*)&a0)[kk];
                float av1 = ((const float*)&a1)[kk];
                float av2 = ((const float*)&a2)[kk];
                float av3 = ((const float*)&a3)[kk];
                acc[0][0] += av0 * bx0; acc[0][1] += av0 * bx1;
                acc[0][2] += av0 * bx2; acc[0][3] += av0 * bx3;
                acc[0][4] += av0 * bx4; acc[0][5] += av0 * bx5;
                acc[0][6] += av0 * bx6; acc[0][7] += av0 * bx7;
                acc[1][0] += av1 * bx0; acc[1][1] += av1 * bx1;
                acc[1][2] += av1 * bx2; acc[1][3] += av1 * bx3;
                acc[1][4] += av1 * bx4; acc[1][5] += av1 * bx5;
                acc[1][6] += av1 * bx6; acc[1][7] += av1 * bx7;
                acc[2][0] += av2 * bx0; acc[2][1] += av2 * bx1;
                acc[2][2] += av2 * bx2; acc[2][3] += av2 * bx3;
                acc[2][4] += av2 * bx4; acc[2][5] += av2 * bx5;
                acc[2][6] += av2 * bx6; acc[2][7] += av2 * bx7;
                acc[3][0] += av3 * bx0; acc[3][1] += av3 * bx1;
                acc[3][2] += av3 * bx2; acc[3][3] += av3 * bx3;
                acc[3][4] += av3 * bx4; acc[3][5] += av3 * bx5;
                acc[3][6] += av3 * bx6; acc[3][7] += av3 * bx7;
            }
        }
        __syncthreads();
    }

    float4 bb0 = *(const float4*)&Bv[c0];
    float4 bb1 = *(const float4*)&Bv[c0 + 64];
#pragma unroll
    for (int i = 0; i < 4; ++i) {
        int row = m0 + r0 + i;
        if (row < M) {
            float4 o0 = make_float4(acc[i][0] + bb0.x, acc[i][1] + bb0.y,
                                    acc[i][2] + bb0.z, acc[i][3] + bb0.w);
            float4 o1 = make_float4(acc[i][4] + bb1.x, acc[i][5] + bb1.y,
                                    acc[i][6] + bb1.z, acc[i][7] + bb1.w);
            *(float4*)&Y[(size_t)row * 128 + c0]      = o0;
            *(float4*)&Y[(size_t)row * 128 + c0 + 64] = o1;
        }
    }
}

// ---------- fused GAT per dst node: one wave per node, online softmax -------
// Lane layout: h = lane>>5 (head), j = lane&31; lane covers channels h*64+j
// and h*64+j+32. 5-step shfl reduce per 32-lane half gives the head logit.
__global__ __launch_bounds__(256) void k_gat(
    const float* __restrict__ xl, const float* __restrict__ xr,
    const float* __restrict__ att, const float* __restrict__ bias,
    const int* __restrict__ rowptr, const int* __restrict__ srcs,
    float* __restrict__ out, int n_dst)
{
    int wave = (blockIdx.x * 256 + threadIdx.x) >> 6;
    if (wave >= n_dst) return;
    const int lane = threadIdx.x & 63;
    const int h = lane >> 5;
    const int j = lane & 31;
    const int c0 = h * 64 + j;
    const int c1 = c0 + 32;
    const int d = wave;

    const int base = rowptr[d];
    const int end  = rowptr[d + 1];
    if (base == end) {                       // empty segment -> out = bias
        if (lane < 32) {
            out[(size_t)d * 64 + j]      = bias[j];
            out[(size_t)d * 64 + j + 32] = bias[j + 32];
        }
        return;
    }

    const float xi0 = xr[(size_t)d * 128 + c0];
    const float xi1 = xr[(size_t)d * 128 + c1];
    const float at0 = att[c0];
    const float at1 = att[c1];

    float m = -3.4e38f, den = 0.f, a0 = 0.f, a1 = 0.f;
    int s = srcs[base];
    for (int k = base; k < end; ++k) {
        int sc = s;
        if (k + 1 < end) s = srcs[k + 1];    // prefetch next src index
        const float* xjp = xl + (size_t)sc * 128;
        float xj0 = xjp[c0];
        float xj1 = xjp[c1];
        float e0 = xi0 + xj0;
        float e1 = xi1 + xj1;
        e0 = e0 >= 0.f ? e0 : 0.2f * e0;
        e1 = e1 >= 0.f ? e1 : 0.2f * e1;
        float p = e0 * at0 + e1 * at1;
        p += __shfl_xor(p, 1, 64);
        p += __shfl_xor(p, 2, 64);
        p += __shfl_xor(p, 4, 64);
        p += __shfl_xor(p, 8, 64);
        p += __shfl_xor(p, 16, 64);          // p = head-h logit in all lanes of half
        float mn  = fmaxf(m, p);
        float scl = __expf(m - mn);
        float w   = __expf(p - mn);
        a0  = a0 * scl + w * xj0;
        a1  = a1 * scl + w * xj1;
        den = den * scl + w;
        m = mn;
    }

    float inv = 1.0f / (den + 1e-16f);
    float r0 = a0 * inv;
    float r1 = a1 * inv;
    float q0 = __shfl_xor(r0, 32, 64);       // other head's same channel
    float q1 = __shfl_xor(r1, 32, 64);
    if (lane < 32) {
        out[(size_t)d * 64 + j]      = 0.5f * (r0 + q0) + bias[j];
        out[(size_t)d * 64 + j + 32] = 0.5f * (r1 + q1) + bias[j + 32];
    }
}

extern "C" void kernel_launch(void* const* d_in, const int* in_sizes, int n_in,
                              void* d_out, int out_size, void* d_ws, size_t ws_size,
                              hipStream_t stream)
{
    const float* x_user   = (const float*)d_in[0];
    const float* x_item   = (const float*)d_in[1];
    const int*   src_u2i  = (const int*)d_in[2];
    const int*   dst_u2i  = (const int*)d_in[3];
    const int*   src_i2u  = (const int*)d_in[4];
    const int*   dst_i2u  = (const int*)d_in[5];
    const float* Wl_u2i   = (const float*)d_in[6];
    const float* bl_u2i   = (const float*)d_in[7];
    const float* Wr_u2i   = (const float*)d_in[8];
    const float* br_u2i   = (const float*)d_in[9];
    const float* att_u2i  = (const float*)d_in[10];
    const float* bias_u2i = (const float*)d_in[11];
    const float* Wl_i2u   = (const float*)d_in[12];
    const float* bl_i2u   = (const float*)d_in[13];
    const float* Wr_i2u   = (const float*)d_in[14];
    const float* br_i2u   = (const float*)d_in[15];
    const float* att_i2u  = (const float*)d_in[16];
    const float* bias_i2u = (const float*)d_in[17];

    const int n_user = in_sizes[0] / 128;
    const int n_item = in_sizes[1] / 128;
    const int E      = in_sizes[2];
    const int n_all  = n_item + n_user;      // cnt/rowptr: [0,n_item)=u2i, rest=i2u

    float* out_user = (float*)d_out;                   // [n_user,64]
    float* out_item = out_user + (size_t)n_user * 64;  // [n_item,64]

    char* w = (char*)d_ws;
    float* xl_u2i = (float*)w; w += (size_t)n_user * 128 * 4;
    float* xr_u2i = (float*)w; w += (size_t)n_item * 128 * 4;
    float* xl_i2u = (float*)w; w += (size_t)n_item * 128 * 4;
    float* xr_i2u = (float*)w; w += (size_t)n_user * 128 * 4;
    int* srcs_all   = (int*)w; w += (size_t)2 * E * 4;
    int* rowptr_all = (int*)w; w += (size_t)(n_all + 1) * 4;
    int* cnt_all    = (int*)w; w += (size_t)n_all * 4;     // reused as cursor
    int* bsum       = (int*)w; w += (size_t)SCAN_B * 4;

    const int nb = (n_all + SCAN_B - 1) / SCAN_B;

    // ---- CSR build (both directions share one scan) ----
    k_zero<<<(n_all + 255) / 256, 256, 0, stream>>>(cnt_all, n_all);
    k_hist<<<(2 * E + 255) / 256, 256, 0, stream>>>(dst_u2i, dst_i2u, cnt_all, n_item, E);
    k_scan1<<<nb, SCAN_B, 0, stream>>>(cnt_all, n_all, rowptr_all, bsum);
    k_scan2<<<1, SCAN_B, 0, stream>>>(bsum, nb);
    k_scan3<<<(n_all + 255) / 256, 256, 0, stream>>>(rowptr_all, cnt_all, bsum, n_all, 2 * E);
    k_fill<<<(2 * E + 255) / 256, 256, 0, stream>>>(
        src_u2i, dst_u2i, src_i2u, dst_i2u, cnt_all, srcs_all, n_item, E);

    // ---- node linear transforms ----
    gemm128<<<(n_user + 63) / 64, 256, 0, stream>>>(x_user, Wl_u2i, bl_u2i, xl_u2i, n_user);
    gemm128<<<(n_item + 63) / 64, 256, 0, stream>>>(x_item, Wr_u2i, br_u2i, xr_u2i, n_item);
    gemm128<<<(n_item + 63) / 64, 256, 0, stream>>>(x_item, Wl_i2u, bl_i2u, xl_i2u, n_item);
    gemm128<<<(n_user + 63) / 64, 256, 0, stream>>>(x_user, Wr_i2u, br_i2u, xr_i2u, n_user);

    // ---- fused single-pass GAT per destination node ----
    k_gat<<<(n_item + 3) / 4, 256, 0, stream>>>(
        xl_u2i, xr_u2i, att_u2i, bias_u2i, rowptr_all, srcs_all, out_item, n_item);
    k_gat<<<(n_user + 3) / 4, 256, 0, stream>>>(
        xl_i2u, xr_i2u, att_i2u, bias_i2u, rowptr_all + n_item, srcs_all, out_user, n_user);
}

// Round 5
// 478.549 us; speedup vs baseline: 1.6550x; 1.0606x over previous
//
#include <hip/hip_runtime.h>

#define SCAN_B 1024

// ---------------- CSR build ----------------
__global__ __launch_bounds__(256) void k_zero(int* __restrict__ cnt, int n) {
    int i = blockIdx.x * 256 + threadIdx.x;
    if (i < n) cnt[i] = 0;
}

__global__ __launch_bounds__(256) void k_hist(
    const int* __restrict__ dst_a, const int* __restrict__ dst_b,
    int* __restrict__ cnt, int n_a, int E)
{
    int i = blockIdx.x * 256 + threadIdx.x;
    if (i >= 2 * E) return;
    int idx = (i < E) ? dst_a[i] : (n_a + dst_b[i - E]);
    atomicAdd(&cnt[idx], 1);
}

__global__ __launch_bounds__(SCAN_B) void k_scan1(
    const int* __restrict__ cnt, int n, int* __restrict__ rowptr, int* __restrict__ bsum)
{
    __shared__ int tmp[SCAN_B];
    int i = blockIdx.x * SCAN_B + threadIdx.x;
    int v = (i < n) ? cnt[i] : 0;
    tmp[threadIdx.x] = v;
    __syncthreads();
    for (int off = 1; off < SCAN_B; off <<= 1) {
        int t = (threadIdx.x >= (unsigned)off) ? tmp[threadIdx.x - off] : 0;
        __syncthreads();
        tmp[threadIdx.x] += t;
        __syncthreads();
    }
    if (i < n) rowptr[i] = tmp[threadIdx.x] - v;   // exclusive
    if (threadIdx.x == SCAN_B - 1) bsum[blockIdx.x] = tmp[threadIdx.x];
}

__global__ __launch_bounds__(SCAN_B) void k_scan2(int* __restrict__ bsum, int nb) {
    __shared__ int tmp[SCAN_B];
    int i = threadIdx.x;
    int v = (i < nb) ? bsum[i] : 0;
    tmp[i] = v;
    __syncthreads();
    for (int off = 1; off < SCAN_B; off <<= 1) {
        int t = (i >= off) ? tmp[i - off] : 0;
        __syncthreads();
        tmp[i] += t;
        __syncthreads();
    }
    if (i < nb) bsum[i] = tmp[i] - v;              // exclusive
}

__global__ __launch_bounds__(256) void k_scan3(
    int* __restrict__ rowptr, int* __restrict__ cursor,
    const int* __restrict__ bsum, int n, int total)
{
    int i = blockIdx.x * 256 + threadIdx.x;
    if (i < n) {
        int r = rowptr[i] + bsum[i / SCAN_B];
        rowptr[i] = r;
        cursor[i] = r;
    }
    if (i == 0) rowptr[n] = total;
}

__global__ __launch_bounds__(256) void k_fill(
    const int* __restrict__ src_a, const int* __restrict__ dst_a,
    const int* __restrict__ src_b, const int* __restrict__ dst_b,
    int* __restrict__ cursor, int* __restrict__ sorted_src, int n_a, int E)
{
    int i = blockIdx.x * 256 + threadIdx.x;
    if (i >= 2 * E) return;
    int idx, s;
    if (i < E) { idx = dst_a[i];            s = src_a[i]; }
    else       { idx = n_a + dst_b[i - E];  s = src_b[i - E]; }
    int pos = atomicAdd(&cursor[idx], 1);
    sorted_src[pos] = s;
}

// ---------- dual GEMM: Y0 = X@W0+B0, Y1 = X@W1+B1  (one X pass) -------------
// 64-row x 256-col (128+128) tile per block, 256 threads, K chunked by 32.
__global__ __launch_bounds__(256) void gemm128x2(
    const float* __restrict__ X,
    const float* __restrict__ W0, const float* __restrict__ B0, float* __restrict__ Y0,
    const float* __restrict__ W1, const float* __restrict__ B1, float* __restrict__ Y1,
    int M)
{
    __shared__ float xs[64][36];     // +4 pad
    __shared__ float ws[32][256];    // cols 0-127 = W0, 128-255 = W1

    const int tid = threadIdx.x;
    const int m0  = blockIdx.x * 64;
    const int r0  = (tid >> 4) * 4;   // 0..60
    const int c0  = (tid & 15) * 4;   // 0..60; covers c0, c0+64 (Y0) and c0+128, c0+192 (Y1)

    float acc[4][16];
#pragma unroll
    for (int i = 0; i < 4; ++i)
#pragma unroll
        for (int j = 0; j < 16; ++j) acc[i][j] = 0.0f;

    for (int kc = 0; kc < 128; kc += 32) {
        // X tile: 64 rows x 32 k (512 float4, 2 per thread)
#pragma unroll
        for (int i = 0; i < 2; ++i) {
            int f = tid + i * 256;
            int row = f >> 3;
            int kq  = (f & 7) * 4;
            float4 v = make_float4(0.f, 0.f, 0.f, 0.f);
            if (m0 + row < M)
                v = *(const float4*)&X[(size_t)(m0 + row) * 128 + kc + kq];
            *(float4*)&xs[row][kq] = v;
        }
        // W tiles: 32 k x 256 n (2048 float4, 8 per thread)
#pragma unroll
        for (int i = 0; i < 8; ++i) {
            int f = tid + i * 256;
            int k = f >> 6;
            int q = (f & 63) * 4;
            float4 v = (q < 128)
                ? *(const float4*)&W0[(size_t)(kc + k) * 128 + q]
                : *(const float4*)&W1[(size_t)(kc + k) * 128 + (q - 128)];
            *(float4*)&ws[k][q] = v;
        }
        __syncthreads();

#pragma unroll
        for (int k = 0; k < 32; k += 4) {
            float4 a0 = *(const float4*)&xs[r0 + 0][k];
            float4 a1 = *(const float4*)&xs[r0 + 1][k];
            float4 a2 = *(const float4*)&xs[r0 + 2][k];
            float4 a3 = *(const float4*)&xs[r0 + 3][k];
#pragma unroll
            for (int kk = 0; kk < 4; ++kk) {
                float4 b0 = *(const float4*)&ws[k + kk][c0];
                float4 b1 = *(const float4*)&ws[k + kk][c0 + 64];
                float4 b2 = *(const float4*)&ws[k + kk][c0 + 128];
                float4 b3 = *(const float4*)&ws[k + kk][c0 + 192];
                float av[4] = { ((const float*)&a0)[kk], ((const float*)&a1)[kk],
                                ((const float*)&a2)[kk], ((const float*)&a3)[kk] };
#pragma unroll
                for (int i = 0; i < 4; ++i) {
                    float a = av[i];
                    acc[i][0]  += a * b0.x; acc[i][1]  += a * b0.y;
                    acc[i][2]  += a * b0.z; acc[i][3]  += a * b0.w;
                    acc[i][4]  += a * b1.x; acc[i][5]  += a * b1.y;
                    acc[i][6]  += a * b1.z; acc[i][7]  += a * b1.w;
                    acc[i][8]  += a * b2.x; acc[i][9]  += a * b2.y;
                    acc[i][10] += a * b2.z; acc[i][11] += a * b2.w;
                    acc[i][12] += a * b3.x; acc[i][13] += a * b3.y;
                    acc[i][14] += a * b3.z; acc[i][15] += a * b3.w;
                }
            }
        }
        __syncthreads();
    }

    float4 p00 = *(const float4*)&B0[c0];
    float4 p01 = *(const float4*)&B0[c0 + 64];
    float4 p10 = *(const float4*)&B1[c0];
    float4 p11 = *(const float4*)&B1[c0 + 64];
#pragma unroll
    for (int i = 0; i < 4; ++i) {
        int row = m0 + r0 + i;
        if (row < M) {
            *(float4*)&Y0[(size_t)row * 128 + c0] = make_float4(
                acc[i][0] + p00.x, acc[i][1] + p00.y, acc[i][2] + p00.z, acc[i][3] + p00.w);
            *(float4*)&Y0[(size_t)row * 128 + c0 + 64] = make_float4(
                acc[i][4] + p01.x, acc[i][5] + p01.y, acc[i][6] + p01.z, acc[i][7] + p01.w);
            *(float4*)&Y1[(size_t)row * 128 + c0] = make_float4(
                acc[i][8] + p10.x, acc[i][9] + p10.y, acc[i][10] + p10.z, acc[i][11] + p10.w);
            *(float4*)&Y1[(size_t)row * 128 + c0 + 64] = make_float4(
                acc[i][12] + p11.x, acc[i][13] + p11.y, acc[i][14] + p11.z, acc[i][15] + p11.w);
        }
    }
}

// ---------- fused GAT, both directions in one grid; one wave per dst node ---
// Lane layout: h = lane>>5 (head), j = lane&31; lane covers channels h*64+j
// and h*64+j+32. Edge loop unrolled by 2: two independent shuffle-reduce
// chains interleave for ILP; 3 expf per 2 edges.
__global__ __launch_bounds__(256) void k_gat2(
    const float* __restrict__ xl_a, const float* __restrict__ xr_a,
    const float* __restrict__ att_a, const float* __restrict__ bias_a,
    float* __restrict__ out_a,
    const float* __restrict__ xl_b, const float* __restrict__ xr_b,
    const float* __restrict__ att_b, const float* __restrict__ bias_b,
    float* __restrict__ out_b,
    const int* __restrict__ rowptr, const int* __restrict__ srcs,
    int n_a, int n_all)
{
    int wave = (blockIdx.x * 256 + threadIdx.x) >> 6;
    if (wave >= n_all) return;
    const int lane = threadIdx.x & 63;
    const int h = lane >> 5;
    const int j = lane & 31;
    const int c0 = h * 64 + j;
    const int c1 = c0 + 32;

    const float *xl, *xr, *att, *bias;
    float* out;
    int d;
    if (wave < n_a) { xl = xl_a; xr = xr_a; att = att_a; bias = bias_a; out = out_a; d = wave; }
    else            { xl = xl_b; xr = xr_b; att = att_b; bias = bias_b; out = out_b; d = wave - n_a; }

    const int base = rowptr[wave];
    const int end  = rowptr[wave + 1];
    if (base == end) {                       // empty segment -> out = bias
        if (lane < 32) {
            out[(size_t)d * 64 + j]      = bias[j];
            out[(size_t)d * 64 + j + 32] = bias[j + 32];
        }
        return;
    }

    const float xi0 = xr[(size_t)d * 128 + c0];
    const float xi1 = xr[(size_t)d * 128 + c1];
    const float at0 = att[c0];
    const float at1 = att[c1];

    float m = -3.4e38f, den = 0.f, a0 = 0.f, a1 = 0.f;
    int k = base;
    for (; k + 1 < end; k += 2) {
        int s0 = srcs[k];
        int s1 = srcs[k + 1];
        const float* xp0 = xl + (size_t)s0 * 128;
        const float* xp1 = xl + (size_t)s1 * 128;
        float x00 = xp0[c0], x01 = xp0[c1];
        float x10 = xp1[c0], x11 = xp1[c1];
        float e00 = xi0 + x00, e01 = xi1 + x01;
        float e10 = xi0 + x10, e11 = xi1 + x11;
        e00 = e00 >= 0.f ? e00 : 0.2f * e00;
        e01 = e01 >= 0.f ? e01 : 0.2f * e01;
        e10 = e10 >= 0.f ? e10 : 0.2f * e10;
        e11 = e11 >= 0.f ? e11 : 0.2f * e11;
        float p0 = e00 * at0 + e01 * at1;
        float p1 = e10 * at0 + e11 * at1;
        // two independent butterflies, interleaved for ILP
        p0 += __shfl_xor(p0, 1, 64);  p1 += __shfl_xor(p1, 1, 64);
        p0 += __shfl_xor(p0, 2, 64);  p1 += __shfl_xor(p1, 2, 64);
        p0 += __shfl_xor(p0, 4, 64);  p1 += __shfl_xor(p1, 4, 64);
        p0 += __shfl_xor(p0, 8, 64);  p1 += __shfl_xor(p1, 8, 64);
        p0 += __shfl_xor(p0, 16, 64); p1 += __shfl_xor(p1, 16, 64);
        float mn  = fmaxf(m, fmaxf(p0, p1));   // v_max3
        float scl = __expf(m - mn);
        float w0  = __expf(p0 - mn);
        float w1  = __expf(p1 - mn);
        den = den * scl + w0 + w1;
        a0  = a0 * scl + w0 * x00 + w1 * x10;
        a1  = a1 * scl + w0 * x01 + w1 * x11;
        m = mn;
    }
    if (k < end) {                            // odd tail
        int s0 = srcs[k];
        const float* xp0 = xl + (size_t)s0 * 128;
        float x00 = xp0[c0], x01 = xp0[c1];
        float e00 = xi0 + x00, e01 = xi1 + x01;
        e00 = e00 >= 0.f ? e00 : 0.2f * e00;
        e01 = e01 >= 0.f ? e01 : 0.2f * e01;
        float p0 = e00 * at0 + e01 * at1;
        p0 += __shfl_xor(p0, 1, 64);
        p0 += __shfl_xor(p0, 2, 64);
        p0 += __shfl_xor(p0, 4, 64);
        p0 += __shfl_xor(p0, 8, 64);
        p0 += __shfl_xor(p0, 16, 64);
        float mn  = fmaxf(m, p0);
        float scl = __expf(m - mn);
        float w0  = __expf(p0 - mn);
        den = den * scl + w0;
        a0  = a0 * scl + w0 * x00;
        a1  = a1 * scl + w0 * x01;
        m = mn;
    }

    float inv = 1.0f / (den + 1e-16f);
    float r0 = a0 * inv;
    float r1 = a1 * inv;
    float q0 = __shfl_xor(r0, 32, 64);        // other head's same channel
    float q1 = __shfl_xor(r1, 32, 64);
    if (lane < 32) {
        out[(size_t)d * 64 + j]      = 0.5f * (r0 + q0) + bias[j];
        out[(size_t)d * 64 + j + 32] = 0.5f * (r1 + q1) + bias[j + 32];
    }
}

extern "C" void kernel_launch(void* const* d_in, const int* in_sizes, int n_in,
                              void* d_out, int out_size, void* d_ws, size_t ws_size,
                              hipStream_t stream)
{
    const float* x_user   = (const float*)d_in[0];
    const float* x_item   = (const float*)d_in[1];
    const int*   src_u2i  = (const int*)d_in[2];
    const int*   dst_u2i  = (const int*)d_in[3];
    const int*   src_i2u  = (const int*)d_in[4];
    const int*   dst_i2u  = (const int*)d_in[5];
    const float* Wl_u2i   = (const float*)d_in[6];
    const float* bl_u2i   = (const float*)d_in[7];
    const float* Wr_u2i   = (const float*)d_in[8];
    const float* br_u2i   = (const float*)d_in[9];
    const float* att_u2i  = (const float*)d_in[10];
    const float* bias_u2i = (const float*)d_in[11];
    const float* Wl_i2u   = (const float*)d_in[12];
    const float* bl_i2u   = (const float*)d_in[13];
    const float* Wr_i2u   = (const float*)d_in[14];
    const float* br_i2u   = (const float*)d_in[15];
    const float* att_i2u  = (const float*)d_in[16];
    const float* bias_i2u = (const float*)d_in[17];

    const int n_user = in_sizes[0] / 128;
    const int n_item = in_sizes[1] / 128;
    const int E      = in_sizes[2];
    const int n_all  = n_item + n_user;      // rowptr: [0,n_item)=u2i, rest=i2u

    float* out_user = (float*)d_out;                   // [n_user,64]
    float* out_item = out_user + (size_t)n_user * 64;  // [n_item,64]

    char* w = (char*)d_ws;
    float* xl_u2i = (float*)w; w += (size_t)n_user * 128 * 4;
    float* xr_u2i = (float*)w; w += (size_t)n_item * 128 * 4;
    float* xl_i2u = (float*)w; w += (size_t)n_item * 128 * 4;
    float* xr_i2u = (float*)w; w += (size_t)n_user * 128 * 4;
    int* srcs_all   = (int*)w; w += (size_t)2 * E * 4;
    int* rowptr_all = (int*)w; w += (size_t)(n_all + 1) * 4;
    int* cnt_all    = (int*)w; w += (size_t)n_all * 4;     // reused as cursor
    int* bsum       = (int*)w; w += (size_t)SCAN_B * 4;

    const int nb = (n_all + SCAN_B - 1) / SCAN_B;

    // ---- CSR build (both directions share one scan) ----
    k_zero<<<(n_all + 255) / 256, 256, 0, stream>>>(cnt_all, n_all);
    k_hist<<<(2 * E + 255) / 256, 256, 0, stream>>>(dst_u2i, dst_i2u, cnt_all, n_item, E);
    k_scan1<<<nb, SCAN_B, 0, stream>>>(cnt_all, n_all, rowptr_all, bsum);
    k_scan2<<<1, SCAN_B, 0, stream>>>(bsum, nb);
    k_scan3<<<(n_all + 255) / 256, 256, 0, stream>>>(rowptr_all, cnt_all, bsum, n_all, 2 * E);
    k_fill<<<(2 * E + 255) / 256, 256, 0, stream>>>(
        src_u2i, dst_u2i, src_i2u, dst_i2u, cnt_all, srcs_all, n_item, E);

    // ---- node linear transforms: one X pass computes both needed projections
    gemm128x2<<<(n_user + 63) / 64, 256, 0, stream>>>(
        x_user, Wl_u2i, bl_u2i, xl_u2i, Wr_i2u, br_i2u, xr_i2u, n_user);
    gemm128x2<<<(n_item + 63) / 64, 256, 0, stream>>>(
        x_item, Wl_i2u, bl_i2u, xl_i2u, Wr_u2i, br_u2i, xr_u2i, n_item);

    // ---- fused single-pass GAT, both directions in one launch ----
    k_gat2<<<(n_all + 3) / 4, 256, 0, stream>>>(
        xl_u2i, xr_u2i, att_u2i, bias_u2i, out_item,
        xl_i2u, xr_i2u, att_i2u, bias_i2u, out_user,
        rowptr_all, srcs_all, n_item, n_all);
}